// Round 2
// baseline (1007.074 us; speedup 1.0000x reference)
//
#include <hip/hip_runtime.h>
#include <hip/hip_bf16.h>

// ConvLayer: 3x3 s1 p1 conv, x=(256,512,512) f32, W=(3,3,256,256) HWIO, out=(256,512,512) f32.
// Strategy: bf16 implicit GEMM on MFMA.
//   xt layout: [h][cg=ci/8][w][8ci]  -> convert_x is LDS-free: 8 coalesced scalar reads
//              pack to one coalesced 16B store. conv staging chunks stay 16B contiguous.
//   wt layout: [kk][cg][co][8ci]     (matching 16B chunks, 256B staging segments)
//   conv_mfma: 128x128 tile, 16x16x32 bf16 MFMA, global_load_lds width16,
//              130-row haloed B tile shared across 3 kw taps, XCD-banded swizzle,
//              launch_bounds(256,4) -> 4 blocks/CU for barrier-drain hiding.

typedef __attribute__((ext_vector_type(8))) short bf16x8;
typedef __attribute__((ext_vector_type(4))) float floatx4;

#define HWSZ 262144   // 512*512
#define CIN  256
#define HH   512
#define WWD  512

__device__ __forceinline__ void async_copy16(const void* g, void* l) {
  __builtin_amdgcn_global_load_lds(
      (const __attribute__((address_space(1))) void*)g,
      (__attribute__((address_space(3))) void*)l, 16, 0, 0);
}

// ---------------- pass 1: x f32 [ci][h][w] -> xt bf16 [h][cg][w][8] ----------------
// grid 1024 = 512 h x 2 w-halves; block 256 thr; no LDS, no barriers.
// Thread owns pixel (h,w): loop 32 cg; read 8 ci (lane-coalesced 256B segments),
// pack 8 bf16 -> one uint4 store (wave-coalesced 1KB lines).
__global__ __launch_bounds__(256) void convert_x(
    const float* __restrict__ x, __hip_bfloat16* __restrict__ xt)
{
  const int b = blockIdx.x;            // 0..1023
  const int h = b >> 1;
  const int w = ((b & 1) << 8) + threadIdx.x;
  const float* xp = x + (size_t)h * WWD + w;
#pragma unroll 2
  for (int cg = 0; cg < 32; ++cg) {
    const float* s = xp + (size_t)(cg << 3) * HWSZ;
    unsigned int q[4];
#pragma unroll
    for (int k = 0; k < 4; ++k) {
      float f0 = s[(size_t)(2 * k) * HWSZ];
      float f1 = s[(size_t)(2 * k + 1) * HWSZ];
      __hip_bfloat16 b0 = __float2bfloat16(f0);
      __hip_bfloat16 b1 = __float2bfloat16(f1);
      q[k] = (unsigned int)*(const unsigned short*)&b0 |
             ((unsigned int)*(const unsigned short*)&b1 << 16);
    }
    uint4 v;
    v.x = q[0]; v.y = q[1]; v.z = q[2]; v.w = q[3];
    *(uint4*)&xt[(((size_t)h * 32 + cg) << 12) + ((size_t)w << 3)] = v;
  }
}

// ---------------- pass 2: W f32 [kh][kw][ci][co] -> wt bf16 [kk][cg][co][8]; zero line ----
__global__ __launch_bounds__(256) void convert_w(
    const float* __restrict__ Wf, __hip_bfloat16* __restrict__ wt,
    __hip_bfloat16* __restrict__ zb)
{
  const int idx = blockIdx.x * 256 + threadIdx.x;   // < 589824
  const int ci = idx & 255;
  const int co = (idx >> 8) & 255;
  const int kk = idx >> 16;                          // 0..8
  wt[(((size_t)(kk * 32 + (ci >> 3)) * 256 + co) << 3) + (ci & 7)] =
      __float2bfloat16(Wf[((size_t)(kk * 256 + ci) << 8) + co]);
  if (idx < 64) zb[idx] = __float2bfloat16(0.0f);
}

// ---------------- pass 3: MFMA implicit-GEMM conv ----------------
// grid 4096; block 256 thr = 4 waves (2x2 of 64x64).
// XCD-banded swizzle: xcd = b&7 owns h-band [xcd*64, xcd*64+64); within band,
// wti fastest, then cot, then h -> 6-fold xt row reuse (3kh x 2cot) stays in per-XCD L2.
__global__ __launch_bounds__(256, 4) void conv_mfma(
    const __hip_bfloat16* __restrict__ xt,   // [512][32][512][8]
    const __hip_bfloat16* __restrict__ wt,   // [9][32][256][8]
    const float* __restrict__ bias,
    float* __restrict__ out,                 // [256][512][512]
    const __hip_bfloat16* __restrict__ zb)
{
  __shared__ __align__(16) __hip_bfloat16 As[3 * 128 * 32];  // [kw][m][k] 24576 B
  __shared__ __align__(16) __hip_bfloat16 Bs[130 * 32];      // [r][k]     8320 B

  const int b     = blockIdx.x;
  const int xcd   = b & 7;
  const int local = b >> 3;            // 0..511
  const int h     = (xcd << 6) + (local >> 3);
  const int rem   = local & 7;
  const int cot   = rem >> 2;
  const int wti   = rem & 3;
  const int w0   = wti << 7;
  const int co0  = cot << 7;
  const int t    = threadIdx.x;
  const int lane = t & 63;
  const int wave = t >> 6;
  const int wm   = wave & 1;    // co half within tile
  const int wn   = wave >> 1;   // w half within tile
  const int mcol = lane & 15;
  const int krow = lane >> 4;

  floatx4 acc[4][4];
#pragma unroll
  for (int mi = 0; mi < 4; ++mi)
#pragma unroll
    for (int ni = 0; ni < 4; ++ni) {
      floatx4 z = {0.f, 0.f, 0.f, 0.f};
      acc[mi][ni] = z;
    }

  for (int kh = 0; kh < 3; ++kh) {
    const int hp = h + kh - 1;
    const bool hok = (unsigned)hp < (unsigned)HH;
    const __hip_bfloat16* xrow = xt + ((size_t)hp << 17);   // [32][512][8]

    for (int ci0 = 0; ci0 < CIN; ci0 += 32) {
      const int cg0 = ci0 >> 3;
      __syncthreads();
      // stage A: 3 kw x 128 co-rows x 64 B  = 1536 16B chunks
#pragma unroll
      for (int rnd = 0; rnd < 6; ++rnd) {
        int c  = rnd * 256 + t;
        int kw = c >> 9;
        int m  = (c >> 2) & 127;
        int j  = c & 3;
        const __hip_bfloat16* g =
            wt + (((size_t)((kh * 3 + kw) * 32 + cg0 + j)) << 11) + ((co0 + m) << 3);
        async_copy16(g, &As[c << 3]);
      }
      // stage B: 130 haloed w-rows x 64 B = 520 chunks
#pragma unroll
      for (int rnd = 0; rnd < 2; ++rnd) {
        int c = rnd * 256 + t;
        int r = c >> 2;
        int j = c & 3;
        int wp = w0 - 1 + r;
        const __hip_bfloat16* g = (hok && (unsigned)wp < (unsigned)WWD)
            ? xrow + ((size_t)(cg0 + j) << 12) + (wp << 3)
            : zb + (j << 3);
        async_copy16(g, &Bs[c << 3]);
      }
      if (t < 8) {
        int c = 512 + t;
        int r = c >> 2;
        int j = c & 3;
        int wp = w0 - 1 + r;
        const __hip_bfloat16* g = (hok && (unsigned)wp < (unsigned)WWD)
            ? xrow + ((size_t)(cg0 + j) << 12) + (wp << 3)
            : zb + (j << 3);
        async_copy16(g, &Bs[c << 3]);
      }
      __syncthreads();

#pragma unroll
      for (int kw = 0; kw < 3; ++kw) {
        bf16x8 af[4], bfr[4];
#pragma unroll
        for (int mi = 0; mi < 4; ++mi)
          af[mi] = *(const bf16x8*)&As[(kw << 12) + ((wm * 64 + mi * 16 + mcol) << 5) + (krow << 3)];
#pragma unroll
        for (int ni = 0; ni < 4; ++ni)
          bfr[ni] = *(const bf16x8*)&Bs[((wn * 64 + ni * 16 + mcol + kw) << 5) + (krow << 3)];
#pragma unroll
        for (int mi = 0; mi < 4; ++mi)
#pragma unroll
          for (int ni = 0; ni < 4; ++ni)
            acc[mi][ni] = __builtin_amdgcn_mfma_f32_16x16x32_bf16(
                af[mi], bfr[ni], acc[mi][ni], 0, 0, 0);
      }
    }
  }

  // epilogue: D col = lane&15, row = (lane>>4)*4 + reg (m91-verified)
  const size_t outrow = (size_t)h * WWD;
#pragma unroll
  for (int mi = 0; mi < 4; ++mi) {
#pragma unroll
    for (int r = 0; r < 4; ++r) {
      int co = co0 + wm * 64 + mi * 16 + krow * 4 + r;
      float bv = bias[co];
      float* op = out + (size_t)co * HWSZ + outrow + w0 + wn * 64 + mcol;
#pragma unroll
      for (int ni = 0; ni < 4; ++ni)
        op[ni * 16] = acc[mi][ni][r] + bv;
    }
  }
}

// ---------------- fallback: naive fp32 direct conv (only if ws too small) ----------------
__global__ __launch_bounds__(256) void conv_naive(
    const float* __restrict__ x, const float* __restrict__ Wf,
    const float* __restrict__ bias, float* __restrict__ out)
{
  size_t idx = (size_t)blockIdx.x * 256 + threadIdx.x;
  int w  = (int)(idx & 511);
  int h  = (int)((idx >> 9) & 511);
  int co = (int)(idx >> 18);
  float acc = bias[co];
  for (int kh = 0; kh < 3; ++kh) {
    int hp = h + kh - 1;
    if ((unsigned)hp >= 512u) continue;
    for (int kw = 0; kw < 3; ++kw) {
      int wp = w + kw - 1;
      if ((unsigned)wp >= 512u) continue;
      const float* wcol = Wf + ((size_t)(kh * 3 + kw) << 16) + co;
      const float* xpix = x + (size_t)hp * 512 + wp;
      for (int ci = 0; ci < 256; ++ci)
        acc += xpix[(size_t)ci * HWSZ] * wcol[(size_t)ci << 8];
    }
  }
  out[idx] = acc;
}

extern "C" void kernel_launch(void* const* d_in, const int* in_sizes, int n_in,
                              void* d_out, int out_size, void* d_ws, size_t ws_size,
                              hipStream_t stream) {
  const float* x    = (const float*)d_in[0];
  const float* Wf   = (const float*)d_in[1];
  const float* bias = (const float*)d_in[2];
  float* out = (float*)d_out;

  const size_t xt_bytes = (size_t)HH * WWD * CIN * 2;        // 134217728
  const size_t wt_bytes = (size_t)9 * 256 * 256 * 2;         // 1179648
  const size_t need = xt_bytes + wt_bytes + 256;

  if (ws_size >= need) {
    __hip_bfloat16* xt = (__hip_bfloat16*)d_ws;
    __hip_bfloat16* wt = (__hip_bfloat16*)((char*)d_ws + xt_bytes);
    __hip_bfloat16* zb = (__hip_bfloat16*)((char*)d_ws + xt_bytes + wt_bytes);
    convert_x<<<1024, 256, 0, stream>>>(x, xt);
    convert_w<<<2304, 256, 0, stream>>>(Wf, wt, zb);
    conv_mfma<<<4096, 256, 0, stream>>>(xt, wt, bias, out, zb);
  } else {
    conv_naive<<<262144, 256, 0, stream>>>(x, Wf, bias, out);
  }
}

// Round 3
// 809.412 us; speedup vs baseline: 1.2442x; 1.2442x over previous
//
#include <hip/hip_runtime.h>
#include <hip/hip_bf16.h>

// ConvLayer: 3x3 s1 p1 conv, x=(256,512,512) f32, W=(3,3,256,256) HWIO, out=(256,512,512) f32.
// Strategy: bf16 implicit GEMM on MFMA.
//   xt layout: [h][cg=ci/8][w][8ci]  -> convert_x is LDS-free streaming.
//   wt layout: [kk][cg][co][8ci]
//   conv_mfma: 128x128 tile, 16x16x32 bf16 MFMA, global_load_lds width16,
//              130-row haloed B tile shared across 3 kw taps, XCD-banded swizzle,
//              T2 chunk-XOR swizzle (chunk ^= (row>>1)&3) on As/Bs: linear LDS dest,
//              inverse-permuted global source, same XOR on ds_read -> 8-way -> free.
//              launch_bounds(256,3): 80 VGPR + 64 acc fits; (256,4) spilled (round-2).

typedef __attribute__((ext_vector_type(8))) short bf16x8;
typedef __attribute__((ext_vector_type(4))) float floatx4;

#define HWSZ 262144   // 512*512
#define CIN  256
#define HH   512
#define WWD  512

__device__ __forceinline__ void async_copy16(const void* g, void* l) {
  __builtin_amdgcn_global_load_lds(
      (const __attribute__((address_space(1))) void*)g,
      (__attribute__((address_space(3))) void*)l, 16, 0, 0);
}

// ---------------- pass 1: x f32 [ci][h][w] -> xt bf16 [h][cg][w][8] ----------------
// grid 1024 = 512 h x 2 w-halves; block 256 thr; no LDS, no barriers.
__global__ __launch_bounds__(256) void convert_x(
    const float* __restrict__ x, __hip_bfloat16* __restrict__ xt)
{
  const int b = blockIdx.x;            // 0..1023
  const int h = b >> 1;
  const int w = ((b & 1) << 8) + threadIdx.x;
  const float* xp = x + (size_t)h * WWD + w;
#pragma unroll 2
  for (int cg = 0; cg < 32; ++cg) {
    const float* s = xp + (size_t)(cg << 3) * HWSZ;
    unsigned int q[4];
#pragma unroll
    for (int k = 0; k < 4; ++k) {
      float f0 = s[(size_t)(2 * k) * HWSZ];
      float f1 = s[(size_t)(2 * k + 1) * HWSZ];
      __hip_bfloat16 b0 = __float2bfloat16(f0);
      __hip_bfloat16 b1 = __float2bfloat16(f1);
      q[k] = (unsigned int)*(const unsigned short*)&b0 |
             ((unsigned int)*(const unsigned short*)&b1 << 16);
    }
    uint4 v;
    v.x = q[0]; v.y = q[1]; v.z = q[2]; v.w = q[3];
    *(uint4*)&xt[(((size_t)h * 32 + cg) << 12) + ((size_t)w << 3)] = v;
  }
}

// ---------------- pass 2: W f32 [kh][kw][ci][co] -> wt bf16 [kk][cg][co][8]; zero line ----
__global__ __launch_bounds__(256) void convert_w(
    const float* __restrict__ Wf, __hip_bfloat16* __restrict__ wt,
    __hip_bfloat16* __restrict__ zb)
{
  const int idx = blockIdx.x * 256 + threadIdx.x;   // < 589824
  const int ci = idx & 255;
  const int co = (idx >> 8) & 255;
  const int kk = idx >> 16;                          // 0..8
  wt[(((size_t)(kk * 32 + (ci >> 3)) * 256 + co) << 3) + (ci & 7)] =
      __float2bfloat16(Wf[((size_t)(kk * 256 + ci) << 8) + co]);
  if (idx < 64) zb[idx] = __float2bfloat16(0.0f);
}

// ---------------- pass 3: MFMA implicit-GEMM conv ----------------
// grid 4096; block 256 thr = 4 waves (2x2 of 64x64).
// XCD-banded swizzle: xcd = b&7 owns h-band [xcd*64, xcd*64+64).
__global__ __launch_bounds__(256, 3) void conv_mfma(
    const __hip_bfloat16* __restrict__ xt,   // [512][32][512][8]
    const __hip_bfloat16* __restrict__ wt,   // [9][32][256][8]
    const float* __restrict__ bias,
    float* __restrict__ out,                 // [256][512][512]
    const __hip_bfloat16* __restrict__ zb)
{
  __shared__ __align__(16) __hip_bfloat16 As[3 * 128 * 32];  // [kw][m][k] 24576 B
  __shared__ __align__(16) __hip_bfloat16 Bs[130 * 32];      // [r][k]     8320 B

  const int b     = blockIdx.x;
  const int xcd   = b & 7;
  const int local = b >> 3;            // 0..511
  const int h     = (xcd << 6) + (local >> 3);
  const int rem   = local & 7;
  const int cot   = rem >> 2;
  const int wti   = rem & 3;
  const int w0   = wti << 7;
  const int co0  = cot << 7;
  const int t    = threadIdx.x;
  const int lane = t & 63;
  const int wave = t >> 6;
  const int wm   = wave & 1;    // co half within tile
  const int wn   = wave >> 1;   // w half within tile
  const int mcol = lane & 15;
  const int krow = lane >> 4;

  // T2 swizzle constants for the staging side (thread-invariant, hoisted):
  // stage A: c -> (kw, m, j); source chunk js = j ^ ((m>>1)&3)
  // stage B: c -> (r, j);     source chunk js = j ^ ((r>>1)&3)

  floatx4 acc[4][4];
#pragma unroll
  for (int mi = 0; mi < 4; ++mi)
#pragma unroll
    for (int ni = 0; ni < 4; ++ni) {
      floatx4 z = {0.f, 0.f, 0.f, 0.f};
      acc[mi][ni] = z;
    }

  for (int kh = 0; kh < 3; ++kh) {
    const int hp = h + kh - 1;
    const bool hok = (unsigned)hp < (unsigned)HH;
    const __hip_bfloat16* xrow = xt + ((size_t)hp << 17);   // [32][512][8]

    for (int ci0 = 0; ci0 < CIN; ci0 += 32) {
      const int cg0 = ci0 >> 3;
      __syncthreads();
      // stage A: 3 kw x 128 co-rows x 64 B  = 1536 16B chunks (chunk-XOR swizzled source)
#pragma unroll
      for (int rnd = 0; rnd < 6; ++rnd) {
        int c  = rnd * 256 + t;
        int kw = c >> 9;
        int m  = (c >> 2) & 127;
        int j  = c & 3;
        int js = j ^ ((m >> 1) & 3);
        const __hip_bfloat16* g =
            wt + (((size_t)((kh * 3 + kw) * 32 + cg0 + js)) << 11) + ((co0 + m) << 3);
        async_copy16(g, &As[c << 3]);
      }
      // stage B: 130 haloed w-rows x 64 B = 520 chunks (chunk-XOR swizzled source)
#pragma unroll
      for (int rnd = 0; rnd < 2; ++rnd) {
        int c = rnd * 256 + t;
        int r = c >> 2;
        int j = c & 3;
        int js = j ^ ((r >> 1) & 3);
        int wp = w0 - 1 + r;
        const __hip_bfloat16* g = (hok && (unsigned)wp < (unsigned)WWD)
            ? xrow + ((size_t)(cg0 + js) << 12) + (wp << 3)
            : zb + (js << 3);
        async_copy16(g, &Bs[c << 3]);
      }
      if (t < 8) {
        int c = 512 + t;
        int r = c >> 2;
        int j = c & 3;
        int js = j ^ ((r >> 1) & 3);
        int wp = w0 - 1 + r;
        const __hip_bfloat16* g = (hok && (unsigned)wp < (unsigned)WWD)
            ? xrow + ((size_t)(cg0 + js) << 12) + (wp << 3)
            : zb + (js << 3);
        async_copy16(g, &Bs[c << 3]);
      }
      __syncthreads();

#pragma unroll
      for (int kw = 0; kw < 3; ++kw) {
        bf16x8 af[4], bfr[4];
#pragma unroll
        for (int mi = 0; mi < 4; ++mi) {
          int row = wm * 64 + mi * 16 + mcol;
          af[mi] = *(const bf16x8*)&As[(kw << 12) + (row << 5) +
                                       ((krow ^ ((row >> 1) & 3)) << 3)];
        }
#pragma unroll
        for (int ni = 0; ni < 4; ++ni) {
          int r = wn * 64 + ni * 16 + mcol + kw;
          bfr[ni] = *(const bf16x8*)&Bs[(r << 5) +
                                        ((krow ^ ((r >> 1) & 3)) << 3)];
        }
#pragma unroll
        for (int mi = 0; mi < 4; ++mi)
#pragma unroll
          for (int ni = 0; ni < 4; ++ni)
            acc[mi][ni] = __builtin_amdgcn_mfma_f32_16x16x32_bf16(
                af[mi], bfr[ni], acc[mi][ni], 0, 0, 0);
      }
    }
  }

  // epilogue: D col = lane&15, row = (lane>>4)*4 + reg (m91-verified)
  const size_t outrow = (size_t)h * WWD;
#pragma unroll
  for (int mi = 0; mi < 4; ++mi) {
#pragma unroll
    for (int r = 0; r < 4; ++r) {
      int co = co0 + wm * 64 + mi * 16 + krow * 4 + r;
      float bv = bias[co];
      float* op = out + (size_t)co * HWSZ + outrow + w0 + wn * 64 + mcol;
#pragma unroll
      for (int ni = 0; ni < 4; ++ni)
        op[ni * 16] = acc[mi][ni][r] + bv;
    }
  }
}

// ---------------- fallback: naive fp32 direct conv (only if ws too small) ----------------
__global__ __launch_bounds__(256) void conv_naive(
    const float* __restrict__ x, const float* __restrict__ Wf,
    const float* __restrict__ bias, float* __restrict__ out)
{
  size_t idx = (size_t)blockIdx.x * 256 + threadIdx.x;
  int w  = (int)(idx & 511);
  int h  = (int)((idx >> 9) & 511);
  int co = (int)(idx >> 18);
  float acc = bias[co];
  for (int kh = 0; kh < 3; ++kh) {
    int hp = h + kh - 1;
    if ((unsigned)hp >= 512u) continue;
    for (int kw = 0; kw < 3; ++kw) {
      int wp = w + kw - 1;
      if ((unsigned)wp >= 512u) continue;
      const float* wcol = Wf + ((size_t)(kh * 3 + kw) << 16) + co;
      const float* xpix = x + (size_t)hp * 512 + wp;
      for (int ci = 0; ci < 256; ++ci)
        acc += xpix[(size_t)ci * HWSZ] * wcol[(size_t)ci << 8];
    }
  }
  out[idx] = acc;
}

extern "C" void kernel_launch(void* const* d_in, const int* in_sizes, int n_in,
                              void* d_out, int out_size, void* d_ws, size_t ws_size,
                              hipStream_t stream) {
  const float* x    = (const float*)d_in[0];
  const float* Wf   = (const float*)d_in[1];
  const float* bias = (const float*)d_in[2];
  float* out = (float*)d_out;

  const size_t xt_bytes = (size_t)HH * WWD * CIN * 2;        // 134217728
  const size_t wt_bytes = (size_t)9 * 256 * 256 * 2;         // 1179648
  const size_t need = xt_bytes + wt_bytes + 256;

  if (ws_size >= need) {
    __hip_bfloat16* xt = (__hip_bfloat16*)d_ws;
    __hip_bfloat16* wt = (__hip_bfloat16*)((char*)d_ws + xt_bytes);
    __hip_bfloat16* zb = (__hip_bfloat16*)((char*)d_ws + xt_bytes + wt_bytes);
    convert_x<<<1024, 256, 0, stream>>>(x, xt);
    convert_w<<<2304, 256, 0, stream>>>(Wf, wt, zb);
    conv_mfma<<<4096, 256, 0, stream>>>(xt, wt, bias, out, zb);
  } else {
    conv_naive<<<262144, 256, 0, stream>>>(x, Wf, bias, out);
  }
}

// Round 4
// 727.000 us; speedup vs baseline: 1.3852x; 1.1134x over previous
//
#include <hip/hip_runtime.h>
#include <hip/hip_bf16.h>

// ConvLayer: 3x3 s1 p1 conv, x=(256,512,512) f32, W=(3,3,256,256) HWIO, out=(256,512,512) f32.
// Strategy: bf16 implicit GEMM on MFMA.
//   xt layout: [h][cg4=ci/32][w][32ci]  -> one K-step row (64B) is contiguous in global,
//              so T2 chunk-XOR (within the 64B line) keeps staging fully coalesced.
//   wt layout: [kk][cg4][co][32ci]
//   conv_mfma: 128x128 tile, 16x16x32 bf16 MFMA, global_load_lds width16,
//              2-phase double-buffered stages (T3 minimum), T2 chunk-XOR swizzle,
//              B tile = 128 rows exactly; halo pixels (w0-1, w0+128) carried in regs
//              and spliced into edge fragments via cndmask. LDS = 64KB exactly.

typedef __attribute__((ext_vector_type(8))) short bf16x8;
typedef __attribute__((ext_vector_type(4))) float floatx4;

#define HWSZ 262144   // 512*512
#define CIN  256
#define HH   512
#define WWD  512

__device__ __forceinline__ void async_copy16(const void* g, void* l) {
  __builtin_amdgcn_global_load_lds(
      (const __attribute__((address_space(1))) void*)g,
      (__attribute__((address_space(3))) void*)l, 16, 0, 0);
}

// ---------------- pass 1: x f32 [ci][h][w] -> xt bf16 [h][cg4][w][32] ----------------
// grid 1024 = 512 h x 2 w-halves; block 256 thr; no LDS.
// Lane quad (q,j): pixel w = base+q, chunk j (ci j*8..j*8+7). Reads: 4 planes x 64B
// segments per instr; writes: 1KB contiguous per wave.
__global__ __launch_bounds__(256) void convert_x(
    const float* __restrict__ x, __hip_bfloat16* __restrict__ xt)
{
  const int b  = blockIdx.x;           // 0..1023
  const int h  = b >> 1;
  const int wh = (b & 1) << 8;         // 0 or 256
  const int t  = threadIdx.x;
  const int q  = t >> 2;               // 0..63
  const int j  = t & 3;                // 16B chunk within pixel row
  const float* xbase = x + (size_t)h * WWD;
#pragma unroll 2
  for (int cg4 = 0; cg4 < 8; ++cg4) {
#pragma unroll
    for (int pass = 0; pass < 4; ++pass) {
      int w = wh + pass * 64 + q;
      const float* s = xbase + (size_t)(cg4 * 32 + j * 8) * HWSZ + w;
      unsigned int qw[4];
#pragma unroll
      for (int k = 0; k < 4; ++k) {
        float f0 = s[(size_t)(2 * k) * HWSZ];
        float f1 = s[(size_t)(2 * k + 1) * HWSZ];
        __hip_bfloat16 b0 = __float2bfloat16(f0);
        __hip_bfloat16 b1 = __float2bfloat16(f1);
        qw[k] = (unsigned int)*(const unsigned short*)&b0 |
                ((unsigned int)*(const unsigned short*)&b1 << 16);
      }
      uint4 v;
      v.x = qw[0]; v.y = qw[1]; v.z = qw[2]; v.w = qw[3];
      *(uint4*)&xt[(((size_t)h * 8 + cg4) << 14) + (w << 5) + (j << 3)] = v;
    }
  }
}

// ---------------- pass 2: W f32 [kh][kw][ci][co] -> wt bf16 [kk][cg4][co][32]; zero line ----
__global__ __launch_bounds__(256) void convert_w(
    const float* __restrict__ Wf, __hip_bfloat16* __restrict__ wt,
    __hip_bfloat16* __restrict__ zb)
{
  const int idx = blockIdx.x * 256 + threadIdx.x;   // < 589824
  const int ci = idx & 255;
  const int co = (idx >> 8) & 255;
  const int kk = idx >> 16;                          // 0..8
  wt[((((size_t)kk * 8 + (ci >> 5)) * 256 + co) << 5) + (ci & 31)] =
      __float2bfloat16(Wf[((size_t)(kk * 256 + ci) << 8) + co]);
  if (idx < 64) zb[idx] = __float2bfloat16(0.0f);
}

// ---------------- pass 3: MFMA implicit-GEMM conv ----------------
// grid 4096; block 256 thr = 4 waves (2x2 of 64x64).
// XCD-banded swizzle: xcd = b&7 owns h-band [xcd*64, xcd*64+64).
__global__ __launch_bounds__(256, 2) void conv_mfma(
    const __hip_bfloat16* __restrict__ xt,   // [512][8][512][32]
    const __hip_bfloat16* __restrict__ wt,   // [9][8][256][32]
    const float* __restrict__ bias,
    float* __restrict__ out,                 // [256][512][512]
    const __hip_bfloat16* __restrict__ zb)
{
  __shared__ __align__(16) __hip_bfloat16 As[2][3 * 128 * 32];  // 49152 B
  __shared__ __align__(16) __hip_bfloat16 Bs[2][128 * 32];      // 16384 B  (total 64KB)

  const int b     = blockIdx.x;
  const int xcd   = b & 7;
  const int local = b >> 3;            // 0..511
  const int h     = (xcd << 6) + (local >> 3);
  const int rem   = local & 7;
  const int cot   = rem >> 2;
  const int wti   = rem & 3;
  const int w0   = wti << 7;
  const int co0  = cot << 7;
  const int t    = threadIdx.x;
  const int lane = t & 63;
  const int wave = t >> 6;
  const int wm   = wave & 1;    // co half within tile
  const int wn   = wave >> 1;   // w half within tile
  const int mcol = lane & 15;
  const int krow = lane >> 4;

  const int  wL   = w0 - 1;
  const int  wR   = w0 + 128;
  const bool wLok = (wL >= 0);
  const bool wRok = (wR < WWD);

  floatx4 acc[4][4];
#pragma unroll
  for (int mi = 0; mi < 4; ++mi)
#pragma unroll
    for (int ni = 0; ni < 4; ++ni) {
      floatx4 z = {0.f, 0.f, 0.f, 0.f};
      acc[mi][ni] = z;
    }

  // ---- stage s (s = kh*8 + cg4) into (Ad, Bd); halo chunks into *hl, *hr ----
  auto STAGE = [&](int s, __hip_bfloat16* Ad, __hip_bfloat16* Bd,
                   bf16x8* hl, bf16x8* hr) {
    const int kh  = s >> 3;
    const int cg4 = s & 7;
    const int hp  = h + kh - 1;
    const bool hok = (unsigned)hp < (unsigned)HH;
    const __hip_bfloat16* xp = xt + (((size_t)hp * 8 + cg4) << 14);
    // A: 3 kw x 128 co-rows x 64B = 1536 chunks (source chunk-XOR within the 64B line)
#pragma unroll
    for (int rnd = 0; rnd < 6; ++rnd) {
      int c  = rnd * 256 + t;
      int kw = c >> 9;
      int m  = (c >> 2) & 127;
      int j  = c & 3;
      int js = j ^ ((m >> 1) & 3);
      const __hip_bfloat16* g =
          wt + ((((size_t)(kh * 3 + kw) * 8 + cg4) * 256 + co0 + m) << 5) + (js << 3);
      async_copy16(g, Ad + (c << 3));
    }
    // B: 128 w-rows x 64B = 512 chunks
#pragma unroll
    for (int rnd = 0; rnd < 2; ++rnd) {
      int c = rnd * 256 + t;
      int r = c >> 2;
      int j = c & 3;
      int js = j ^ ((r >> 1) & 3);
      const __hip_bfloat16* g = hok ? xp + ((w0 + r) << 5) + (js << 3)
                                    : zb + (js << 3);
      async_copy16(g, Bd + (c << 3));
    }
    // halo chunks (per-lane krow slice of pixels w0-1 and w0+128), direct to regs
    const __hip_bfloat16* gl = (hok && wLok) ? xp + (wL << 5) + (krow << 3) : zb;
    const __hip_bfloat16* gr = (hok && wRok) ? xp + (wR << 5) + (krow << 3) : zb;
    *hl = *(const bf16x8*)gl;
    *hr = *(const bf16x8*)gr;
  };

  // ---- compute one stage from (A, B) with halo regs ----
  auto COMPUTE = [&](const __hip_bfloat16* A, const __hip_bfloat16* B,
                     bf16x8 hl, bf16x8 hr) {
#pragma unroll
    for (int kw = 0; kw < 3; ++kw) {
      bf16x8 af[4], bfr[4];
#pragma unroll
      for (int mi = 0; mi < 4; ++mi) {
        int row = wm * 64 + mi * 16 + mcol;
        af[mi] = *(const bf16x8*)&A[(kw << 12) + (row << 5) +
                                    ((krow ^ ((row >> 1) & 3)) << 3)];
      }
#pragma unroll
      for (int ni = 0; ni < 4; ++ni) {
        int r  = wn * 64 + ni * 16 + mcol + kw - 1;
        int rc = r & 127;
        bfr[ni] = *(const bf16x8*)&B[(rc << 5) +
                                     ((krow ^ ((rc >> 1) & 3)) << 3)];
      }
      if (kw == 0) {                       // left edge: row -1 -> halo reg
        bool c = (wn == 0) && (mcol == 0);
        bfr[0] = c ? hl : bfr[0];
      }
      if (kw == 2) {                       // right edge: row 128 -> halo reg
        bool c = (wn == 1) && (mcol == 15);
        bfr[3] = c ? hr : bfr[3];
      }
#pragma unroll
      for (int mi = 0; mi < 4; ++mi)
#pragma unroll
        for (int ni = 0; ni < 4; ++ni)
          acc[mi][ni] = __builtin_amdgcn_mfma_f32_16x16x32_bf16(
              af[mi], bfr[ni], acc[mi][ni], 0, 0, 0);
    }
  };

  bf16x8 hl0, hr0, hl1, hr1;
  STAGE(0, As[0], Bs[0], &hl0, &hr0);
  __syncthreads();                          // drain + barrier

  for (int ss = 0; ss < 12; ++ss) {
    const int s = ss * 2;
    STAGE(s + 1, As[1], Bs[1], &hl1, &hr1); // prefetch odd stage
    COMPUTE(As[0], Bs[0], hl0, hr0);
    __syncthreads();
    if (s + 2 < 24) STAGE(s + 2, As[0], Bs[0], &hl0, &hr0);  // prefetch next even
    COMPUTE(As[1], Bs[1], hl1, hr1);
    __syncthreads();
  }

  // epilogue: D col = lane&15, row = (lane>>4)*4 + reg (m91-verified)
  const size_t outrow = (size_t)h * WWD;
#pragma unroll
  for (int mi = 0; mi < 4; ++mi) {
#pragma unroll
    for (int r = 0; r < 4; ++r) {
      int co = co0 + wm * 64 + mi * 16 + krow * 4 + r;
      float bv = bias[co];
      float* op = out + (size_t)co * HWSZ + outrow + w0 + wn * 64 + mcol;
#pragma unroll
      for (int ni = 0; ni < 4; ++ni)
        op[ni * 16] = acc[mi][ni][r] + bv;
    }
  }
}

// ---------------- fallback: naive fp32 direct conv (only if ws too small) ----------------
__global__ __launch_bounds__(256) void conv_naive(
    const float* __restrict__ x, const float* __restrict__ Wf,
    const float* __restrict__ bias, float* __restrict__ out)
{
  size_t idx = (size_t)blockIdx.x * 256 + threadIdx.x;
  int w  = (int)(idx & 511);
  int h  = (int)((idx >> 9) & 511);
  int co = (int)(idx >> 18);
  float acc = bias[co];
  for (int kh = 0; kh < 3; ++kh) {
    int hp = h + kh - 1;
    if ((unsigned)hp >= 512u) continue;
    for (int kw = 0; kw < 3; ++kw) {
      int wp = w + kw - 1;
      if ((unsigned)wp >= 512u) continue;
      const float* wcol = Wf + ((size_t)(kh * 3 + kw) << 16) + co;
      const float* xpix = x + (size_t)hp * 512 + wp;
      for (int ci = 0; ci < 256; ++ci)
        acc += xpix[(size_t)ci * HWSZ] * wcol[(size_t)ci << 8];
    }
  }
  out[idx] = acc;
}

extern "C" void kernel_launch(void* const* d_in, const int* in_sizes, int n_in,
                              void* d_out, int out_size, void* d_ws, size_t ws_size,
                              hipStream_t stream) {
  const float* x    = (const float*)d_in[0];
  const float* Wf   = (const float*)d_in[1];
  const float* bias = (const float*)d_in[2];
  float* out = (float*)d_out;

  const size_t xt_bytes = (size_t)HH * WWD * CIN * 2;        // 134217728
  const size_t wt_bytes = (size_t)9 * 256 * 256 * 2;         // 1179648
  const size_t need = xt_bytes + wt_bytes + 256;

  if (ws_size >= need) {
    __hip_bfloat16* xt = (__hip_bfloat16*)d_ws;
    __hip_bfloat16* wt = (__hip_bfloat16*)((char*)d_ws + xt_bytes);
    __hip_bfloat16* zb = (__hip_bfloat16*)((char*)d_ws + xt_bytes + wt_bytes);
    convert_x<<<1024, 256, 0, stream>>>(x, xt);
    convert_w<<<2304, 256, 0, stream>>>(Wf, wt, zb);
    conv_mfma<<<4096, 256, 0, stream>>>(xt, wt, bias, out, zb);
  } else {
    conv_naive<<<262144, 256, 0, stream>>>(x, Wf, bias, out);
  }
}

// Round 5
// 699.917 us; speedup vs baseline: 1.4388x; 1.0387x over previous
//
#include <hip/hip_runtime.h>
#include <hip/hip_bf16.h>

// ConvLayer: 3x3 s1 p1 conv, x=(256,512,512) f32, W=(3,3,256,256) HWIO, out=(256,512,512) f32.
// Strategy: bf16 implicit GEMM on MFMA.
//   xt layout: [h][cg4=ci/32][w][32ci]  -> one K-step row (64B) contiguous in global,
//              so chunk-XOR swizzle (within the 64B line) keeps staging fully coalesced.
//   wt layout: [kk][cg4][co][32ci]
//   conv_mfma: 128x128 tile, 16x16x32 bf16 MFMA, global_load_lds width16,
//              SINGLE-buffered 33KB LDS (r1-winning occupancy: 4 blocks/CU) +
//              conflict-free chunk-XOR swizzle (r4-winning, BANK_CONFLICT=0).
//              r4's 64KB double-buffer lost to occupancy (2 blocks/CU, 345us vs 307).
//              130-row haloed B tile shared across 3 kw taps; XCD-banded swizzle.

typedef __attribute__((ext_vector_type(8))) short bf16x8;
typedef __attribute__((ext_vector_type(4))) float floatx4;

#define HWSZ 262144   // 512*512
#define CIN  256
#define HH   512
#define WWD  512

__device__ __forceinline__ void async_copy16(const void* g, void* l) {
  __builtin_amdgcn_global_load_lds(
      (const __attribute__((address_space(1))) void*)g,
      (__attribute__((address_space(3))) void*)l, 16, 0, 0);
}

// ---------------- pass 1: x f32 [ci][h][w] -> xt bf16 [h][cg4][w][32] ----------------
// grid 1024 = 512 h x 2 w-halves; block 256 thr; no LDS.
__global__ __launch_bounds__(256) void convert_x(
    const float* __restrict__ x, __hip_bfloat16* __restrict__ xt)
{
  const int b  = blockIdx.x;           // 0..1023
  const int h  = b >> 1;
  const int wh = (b & 1) << 8;         // 0 or 256
  const int t  = threadIdx.x;
  const int q  = t >> 2;               // 0..63
  const int j  = t & 3;                // 16B chunk within pixel row
  const float* xbase = x + (size_t)h * WWD;
#pragma unroll 2
  for (int cg4 = 0; cg4 < 8; ++cg4) {
#pragma unroll
    for (int pass = 0; pass < 4; ++pass) {
      int w = wh + pass * 64 + q;
      const float* s = xbase + (size_t)(cg4 * 32 + j * 8) * HWSZ + w;
      unsigned int qw[4];
#pragma unroll
      for (int k = 0; k < 4; ++k) {
        float f0 = s[(size_t)(2 * k) * HWSZ];
        float f1 = s[(size_t)(2 * k + 1) * HWSZ];
        __hip_bfloat16 b0 = __float2bfloat16(f0);
        __hip_bfloat16 b1 = __float2bfloat16(f1);
        qw[k] = (unsigned int)*(const unsigned short*)&b0 |
                ((unsigned int)*(const unsigned short*)&b1 << 16);
      }
      uint4 v;
      v.x = qw[0]; v.y = qw[1]; v.z = qw[2]; v.w = qw[3];
      *(uint4*)&xt[(((size_t)h * 8 + cg4) << 14) + (w << 5) + (j << 3)] = v;
    }
  }
}

// ---------------- pass 2: W f32 [kh][kw][ci][co] -> wt bf16 [kk][cg4][co][32]; zero line ----
__global__ __launch_bounds__(256) void convert_w(
    const float* __restrict__ Wf, __hip_bfloat16* __restrict__ wt,
    __hip_bfloat16* __restrict__ zb)
{
  const int idx = blockIdx.x * 256 + threadIdx.x;   // < 589824
  const int ci = idx & 255;
  const int co = (idx >> 8) & 255;
  const int kk = idx >> 16;                          // 0..8
  wt[((((size_t)kk * 8 + (ci >> 5)) * 256 + co) << 5) + (ci & 31)] =
      __float2bfloat16(Wf[((size_t)(kk * 256 + ci) << 8) + co]);
  if (idx < 64) zb[idx] = __float2bfloat16(0.0f);
}

// ---------------- pass 3: MFMA implicit-GEMM conv ----------------
// grid 4096; block 256 thr = 4 waves (2x2 of 64x64).
// XCD-banded swizzle: xcd = b&7 owns h-band [xcd*64, xcd*64+64).
__global__ __launch_bounds__(256, 3) void conv_mfma(
    const __hip_bfloat16* __restrict__ xt,   // [512][8][512][32]
    const __hip_bfloat16* __restrict__ wt,   // [9][8][256][32]
    const float* __restrict__ bias,
    float* __restrict__ out,                 // [256][512][512]
    const __hip_bfloat16* __restrict__ zb)
{
  __shared__ __align__(16) __hip_bfloat16 As[3 * 128 * 32];  // 24576 B
  __shared__ __align__(16) __hip_bfloat16 Bs[130 * 32];      // 8320 B  (32896 total)

  const int b     = blockIdx.x;
  const int xcd   = b & 7;
  const int local = b >> 3;            // 0..511
  const int h     = (xcd << 6) + (local >> 3);
  const int rem   = local & 7;
  const int cot   = rem >> 2;
  const int wti   = rem & 3;
  const int w0   = wti << 7;
  const int co0  = cot << 7;
  const int t    = threadIdx.x;
  const int lane = t & 63;
  const int wave = t >> 6;
  const int wm   = wave & 1;    // co half within tile
  const int wn   = wave >> 1;   // w half within tile
  const int mcol = lane & 15;
  const int krow = lane >> 4;

  floatx4 acc[4][4];
#pragma unroll
  for (int mi = 0; mi < 4; ++mi)
#pragma unroll
    for (int ni = 0; ni < 4; ++ni) {
      floatx4 z = {0.f, 0.f, 0.f, 0.f};
      acc[mi][ni] = z;
    }

  for (int kh = 0; kh < 3; ++kh) {
    const int hp  = h + kh - 1;
    const bool hok = (unsigned)hp < (unsigned)HH;

    for (int cg4 = 0; cg4 < 8; ++cg4) {
      const __hip_bfloat16* xp = xt + (((size_t)hp * 8 + cg4) << 14);
      __syncthreads();
      // stage A: 3 kw x 128 co-rows x 64B = 1536 chunks (source chunk-XOR in 64B line)
#pragma unroll
      for (int rnd = 0; rnd < 6; ++rnd) {
        int c  = rnd * 256 + t;
        int kw = c >> 9;
        int m  = (c >> 2) & 127;
        int j  = c & 3;
        int js = j ^ ((m >> 1) & 3);
        const __hip_bfloat16* g =
            wt + ((((size_t)(kh * 3 + kw) * 8 + cg4) * 256 + co0 + m) << 5) + (js << 3);
        async_copy16(g, &As[c << 3]);
      }
      // stage B: 130 haloed w-rows x 64B = 520 chunks
#pragma unroll
      for (int rnd = 0; rnd < 2; ++rnd) {
        int c = rnd * 256 + t;
        int r = c >> 2;
        int j = c & 3;
        int js = j ^ ((r >> 1) & 3);
        int wp = w0 - 1 + r;
        const __hip_bfloat16* g = (hok && (unsigned)wp < (unsigned)WWD)
            ? xp + (wp << 5) + (js << 3)
            : zb + (js << 3);
        async_copy16(g, &Bs[c << 3]);
      }
      if (t < 8) {
        int c = 512 + t;
        int r = c >> 2;
        int j = c & 3;
        int js = j ^ ((r >> 1) & 3);
        int wp = w0 - 1 + r;
        const __hip_bfloat16* g = (hok && (unsigned)wp < (unsigned)WWD)
            ? xp + (wp << 5) + (js << 3)
            : zb + (js << 3);
        async_copy16(g, &Bs[c << 3]);
      }
      __syncthreads();

#pragma unroll
      for (int kw = 0; kw < 3; ++kw) {
        bf16x8 af[4], bfr[4];
#pragma unroll
        for (int mi = 0; mi < 4; ++mi) {
          int row = wm * 64 + mi * 16 + mcol;
          af[mi] = *(const bf16x8*)&As[(kw << 12) + (row << 5) +
                                       ((krow ^ ((row >> 1) & 3)) << 3)];
        }
#pragma unroll
        for (int ni = 0; ni < 4; ++ni) {
          int r = wn * 64 + ni * 16 + mcol + kw;   // 0..129 in haloed Bs
          bfr[ni] = *(const bf16x8*)&Bs[(r << 5) +
                                        ((krow ^ ((r >> 1) & 3)) << 3)];
        }
#pragma unroll
        for (int mi = 0; mi < 4; ++mi)
#pragma unroll
          for (int ni = 0; ni < 4; ++ni)
            acc[mi][ni] = __builtin_amdgcn_mfma_f32_16x16x32_bf16(
                af[mi], bfr[ni], acc[mi][ni], 0, 0, 0);
      }
    }
  }

  // epilogue: D col = lane&15, row = (lane>>4)*4 + reg (m91-verified)
  const size_t outrow = (size_t)h * WWD;
#pragma unroll
  for (int mi = 0; mi < 4; ++mi) {
#pragma unroll
    for (int r = 0; r < 4; ++r) {
      int co = co0 + wm * 64 + mi * 16 + krow * 4 + r;
      float bv = bias[co];
      float* op = out + (size_t)co * HWSZ + outrow + w0 + wn * 64 + mcol;
#pragma unroll
      for (int ni = 0; ni < 4; ++ni)
        op[ni * 16] = acc[mi][ni][r] + bv;
    }
  }
}

// ---------------- fallback: naive fp32 direct conv (only if ws too small) ----------------
__global__ __launch_bounds__(256) void conv_naive(
    const float* __restrict__ x, const float* __restrict__ Wf,
    const float* __restrict__ bias, float* __restrict__ out)
{
  size_t idx = (size_t)blockIdx.x * 256 + threadIdx.x;
  int w  = (int)(idx & 511);
  int h  = (int)((idx >> 9) & 511);
  int co = (int)(idx >> 18);
  float acc = bias[co];
  for (int kh = 0; kh < 3; ++kh) {
    int hp = h + kh - 1;
    if ((unsigned)hp >= 512u) continue;
    for (int kw = 0; kw < 3; ++kw) {
      int wp = w + kw - 1;
      if ((unsigned)wp >= 512u) continue;
      const float* wcol = Wf + ((size_t)(kh * 3 + kw) << 16) + co;
      const float* xpix = x + (size_t)hp * 512 + wp;
      for (int ci = 0; ci < 256; ++ci)
        acc += xpix[(size_t)ci * HWSZ] * wcol[(size_t)ci << 8];
    }
  }
  out[idx] = acc;
}

extern "C" void kernel_launch(void* const* d_in, const int* in_sizes, int n_in,
                              void* d_out, int out_size, void* d_ws, size_t ws_size,
                              hipStream_t stream) {
  const float* x    = (const float*)d_in[0];
  const float* Wf   = (const float*)d_in[1];
  const float* bias = (const float*)d_in[2];
  float* out = (float*)d_out;

  const size_t xt_bytes = (size_t)HH * WWD * CIN * 2;        // 134217728
  const size_t wt_bytes = (size_t)9 * 256 * 256 * 2;         // 1179648
  const size_t need = xt_bytes + wt_bytes + 256;

  if (ws_size >= need) {
    __hip_bfloat16* xt = (__hip_bfloat16*)d_ws;
    __hip_bfloat16* wt = (__hip_bfloat16*)((char*)d_ws + xt_bytes);
    __hip_bfloat16* zb = (__hip_bfloat16*)((char*)d_ws + xt_bytes + wt_bytes);
    convert_x<<<1024, 256, 0, stream>>>(x, xt);
    convert_w<<<2304, 256, 0, stream>>>(Wf, wt, zb);
    conv_mfma<<<4096, 256, 0, stream>>>(xt, wt, bias, out, zb);
  } else {
    conv_naive<<<262144, 256, 0, stream>>>(x, Wf, bias, out);
  }
}